// Round 3
// baseline (144.050 us; speedup 1.0000x reference)
//
#include <hip/hip_runtime.h>

static constexpr int C    = 64;
static constexpr int H    = 128;
static constexpr int W    = 128;
static constexpr int NPIX = H * W;      // 16384

// ---------------------------------------------------------------------------
// A) Per-(h-row, w-half) fused conv1x1(q,k,v) + horizontal v-sum + row-gram +
//    diagonal 7-sum. grid (128, 2) = 256 blocks x 512 threads, 1 block/CU.
//    LDS plan (floats), 33280 total = 130 KB:
//      xs  [64][128] @0      x row h
//      vs  [64][128] @8192   v row h
//      qs2 [64][136] @16384  q row, col index shifted +3, zero guard cols
//                            [0,3) and [131,136)  -> OOB w' reads give 0
//      ks  [64][128] @25088  k row
//      G   [72][132] @0      gram tile, overlays xs+vs after vh phase
// ---------------------------------------------------------------------------
__global__ __launch_bounds__(512, 2) void k_rowA(
    const float* __restrict__ x,
    const float* __restrict__ Wq, const float* __restrict__ bq,
    const float* __restrict__ Wk, const float* __restrict__ bk,
    const float* __restrict__ Wv, const float* __restrict__ bv,
    float* __restrict__ Sd, float* __restrict__ vh)
{
    __shared__ float lds[33280];                        // 130 KB
    float (*xs)[128]  = (float(*)[128])(lds);           // [64][128]
    float (*vs)[128]  = (float(*)[128])(lds + 8192);    // [64][128]
    float (*qs2)[136] = (float(*)[136])(lds + 16384);   // [64][136]
    float (*ks)[128]  = (float(*)[128])(lds + 25088);   // [64][128]
    float (*G)[132]   = (float(*)[132])(lds);           // [72][132] overlay

    const int h   = blockIdx.x;
    const int w0  = blockIdx.y * 64;
    const int tid = threadIdx.x;

    // ---- stage x row h (32 KB, coalesced float4) ----
#pragma unroll
    for (int r = 0; r < 4; ++r) {
        int f  = tid + r * 512;          // 0..2047 float4
        int c  = f >> 5;
        int k4 = (f & 31) << 2;
        *(float4*)(&xs[c][k4]) =
            *(const float4*)(x + (size_t)c * NPIX + h * W + k4);
    }
    // zero qs2 guard columns {0,1,2, 131..135}
    {
        int c   = tid >> 3;
        int g   = tid & 7;
        int col = (g < 3) ? g : (g + 128);
        qs2[c][col] = 0.f;
    }
    __syncthreads();

    // ---- conv1x1: col = tid&127, wg = tid>>7 owns 16 c_out; q,k,v in one
    //      pass (48 independent acc chains, W/b via wave-uniform s_loads) ----
    {
        const int col = tid & 127;
        const int c0  = __builtin_amdgcn_readfirstlane((tid >> 7) * 16);

        float aq[16], ak[16], av[16];
#pragma unroll
        for (int j = 0; j < 16; ++j) {
            aq[j] = bq[c0 + j]; ak[j] = bk[c0 + j]; av[j] = bv[c0 + j];
        }
#pragma unroll 4
        for (int c = 0; c < 64; ++c) {
            const float xv = xs[c][col];
#pragma unroll
            for (int j = 0; j < 16; ++j) {
                aq[j] += Wq[(c0 + j) * 64 + c] * xv;
                ak[j] += Wk[(c0 + j) * 64 + c] * xv;
                av[j] += Wv[(c0 + j) * 64 + c] * xv;
            }
        }
#pragma unroll
        for (int j = 0; j < 16; ++j) {
            qs2[c0 + j][col + 3] = aq[j];      // shifted q image
            ks [c0 + j][col]     = ak[j];
            vs [c0 + j][col]     = av[j];
        }
    }
    __syncthreads();

    const int lane = tid & 63;
    const int wg8  = tid >> 6;               // 0..7

    // ---- horizontal 7-sum of v -> vh[c][h][w] (this half's w range) ----
#pragma unroll
    for (int j = 0; j < 8; ++j) {
        int c = wg8 * 8 + j;
        float s = 0.f;
#pragma unroll
        for (int d = -3; d <= 3; ++d) {
            int wj = w0 + lane + d;
            if (wj >= 0 && wj < W) s += vs[c][wj];
        }
        vh[(size_t)c * NPIX + h * W + w0 + lane] = s;
    }

    // ---- k fragments to registers: this lane's kk and kk+64 columns ----
    float k0[64], k1[64];
#pragma unroll
    for (int c = 0; c < 64; ++c) {
        k0[c] = ks[c][lane];
        k1[c] = ks[c][lane + 64];
    }
    __syncthreads();     // vs reads done -> G may overlay xs/vs

    // ---- row gram: G[w'l][kk] = sum_c q[c][w0-3+w'l] * k[c][kk]
    //      w'l in [0,72), 18 tiles of 4; 2 kk per thread (lane, lane+64).
    //      qs2 guard cols make OOB w' contributions exactly 0. ----
    for (int tile = wg8; tile < 18; tile += 8) {
        float ax0 = 0.f, ax1 = 0.f, ay0 = 0.f, ay1 = 0.f;
        float az0 = 0.f, az1 = 0.f, aw0 = 0.f, aw1 = 0.f;
#pragma unroll
        for (int c = 0; c < 64; ++c) {
            float4 qv = *(const float4*)(&qs2[c][w0 + 4 * tile]); // broadcast
            ax0 += qv.x * k0[c]; ax1 += qv.x * k1[c];
            ay0 += qv.y * k0[c]; ay1 += qv.y * k1[c];
            az0 += qv.z * k0[c]; az1 += qv.z * k1[c];
            aw0 += qv.w * k0[c]; aw1 += qv.w * k1[c];
        }
        const int wl4 = 4 * tile;
        G[wl4 + 0][lane] = ax0;  G[wl4 + 0][lane + 64] = ax1;
        G[wl4 + 1][lane] = ay0;  G[wl4 + 1][lane + 64] = ay1;
        G[wl4 + 2][lane] = az0;  G[wl4 + 2][lane + 64] = az1;
        G[wl4 + 3][lane] = aw0;  G[wl4 + 3][lane + 64] = aw1;
    }
    __syncthreads();

    // ---- diagonal 7-sum -> Sd[h][w][kk] ----
    {
        const int kk  = tid & 127;
        const int wg4 = tid >> 7;            // 0..3
#pragma unroll
        for (int r = 0; r < 16; ++r) {
            int wl = wg4 * 16 + r;           // 0..63 (w = w0 + wl)
            float s = 0.f;
#pragma unroll
            for (int j = 0; j < 7; ++j) {
                int kj = kk + j - 3;
                if (kj >= 0 && kj < W) s += G[wl + j][kj];
            }
            Sd[((size_t)h * W + w0 + wl) * W + kk] = s;
        }
    }
}

// ---------------------------------------------------------------------------
// B) Fused vertical-7-sums + softmax + PV. grid (128, 2) x 512 threads.
//    Vl[c][kk] = sum_i vh[c][h+i-3][kk] accumulated in registers (replaces
//    the old box kernel's vertical pass); logits = sum_i Sd[h+i-3][w][kk];
//    8-lane shuffle softmax into LDS; 64w x 64c x 128kk PV from LDS.
// ---------------------------------------------------------------------------
__global__ __launch_bounds__(512, 2) void k_rowB(
    const float* __restrict__ Sd, const float* __restrict__ vh,
    float* __restrict__ out)
{
    constexpr int AP = 129;
    __shared__ float At[64][AP];     // attn[w-local][kk], 33.0 KB
    __shared__ float Vl[64][128];    // V box-sum[c][kk],  32.8 KB

    const int h   = blockIdx.x;
    const int w0  = blockIdx.y * 64;
    const int tid = threadIdx.x;

    // ---- vertical 7-sum of vh into register tile (issues early) ----
    float4 va[4];
#pragma unroll
    for (int r = 0; r < 4; ++r) va[r] = make_float4(0.f, 0.f, 0.f, 0.f);
#pragma unroll
    for (int i = 0; i < 7; ++i) {
        int hp = h - 3 + i;                  // block-uniform branch
        if (hp >= 0 && hp < H) {
#pragma unroll
            for (int r = 0; r < 4; ++r) {
                int L  = tid + r * 512;
                int c  = L >> 5;
                int k4 = (L & 31) << 2;
                float4 t = *(const float4*)(vh + (size_t)c * NPIX + hp * W + k4);
                va[r].x += t.x; va[r].y += t.y; va[r].z += t.z; va[r].w += t.w;
            }
        }
    }

    // ---- logits: vertical 7-sum of Sd ----
    const int wl = tid >> 3;             // 0..63
    const int s  = tid & 7;              // kk octant

    float4 g0 = make_float4(0.f, 0.f, 0.f, 0.f);
    float4 g1 = g0, g2 = g0, g3 = g0;
#pragma unroll
    for (int i = 0; i < 7; ++i) {
        int hp = h - 3 + i;
        if (hp >= 0 && hp < H) {
            const float4* src = (const float4*)(
                Sd + (size_t)hp * NPIX + (w0 + wl) * W + s * 16);
            float4 a = src[0], b = src[1], c2 = src[2], d = src[3];
            g0.x += a.x;  g0.y += a.y;  g0.z += a.z;  g0.w += a.w;
            g1.x += b.x;  g1.y += b.y;  g1.z += b.z;  g1.w += b.w;
            g2.x += c2.x; g2.y += c2.y; g2.z += c2.z; g2.w += c2.w;
            g3.x += d.x;  g3.y += d.y;  g3.z += d.z;  g3.w += d.w;
        }
    }

    float lg[16] = { g0.x, g0.y, g0.z, g0.w,  g1.x, g1.y, g1.z, g1.w,
                     g2.x, g2.y, g2.z, g2.w,  g3.x, g3.y, g3.z, g3.w };

    float m = lg[0];
#pragma unroll
    for (int e = 1; e < 16; ++e) m = fmaxf(m, lg[e]);
#pragma unroll
    for (int off = 1; off <= 4; off <<= 1) m = fmaxf(m, __shfl_xor(m, off));

    float ssum = 0.f;
#pragma unroll
    for (int e = 0; e < 16; ++e) { lg[e] = __expf(lg[e] - m); ssum += lg[e]; }
#pragma unroll
    for (int off = 1; off <= 4; off <<= 1) ssum += __shfl_xor(ssum, off);
    const float inv = 1.f / ssum;

#pragma unroll
    for (int e = 0; e < 16; ++e) At[wl][s * 16 + e] = lg[e] * inv;

    // ---- land Vl, sync ----
#pragma unroll
    for (int r = 0; r < 4; ++r) {
        int L  = tid + r * 512;
        int c  = L >> 5;
        int k4 = (L & 31) << 2;
        *(float4*)(&Vl[c][k4]) = va[r];
    }
    __syncthreads();

    // ---- PV: out[c, h, w0+w2] = sum_kk At[w2][kk] * Vl[c][kk] ----
    const int w2 = tid & 63;
    const int c0 = __builtin_amdgcn_readfirstlane((tid >> 6) * 8);

    float acc[8];
#pragma unroll
    for (int j = 0; j < 8; ++j) acc[j] = 0.f;

    for (int kk = 0; kk < 128; kk += 4) {
        float4 a = *(const float4*)(&At[w2][kk]);
#pragma unroll
        for (int j = 0; j < 8; ++j) {
            float4 vv = *(const float4*)(&Vl[c0 + j][kk]);   // broadcast
            acc[j] += a.x * vv.x + a.y * vv.y + a.z * vv.z + a.w * vv.w;
        }
    }

#pragma unroll
    for (int j = 0; j < 8; ++j)
        out[(size_t)(c0 + j) * NPIX + h * W + w0 + w2] = acc[j];
}

// ---------------------------------------------------------------------------
// Workspace: 3M floats = 12 MB used:  Sd [0, 2M)   vh [2M, 3M)
// ---------------------------------------------------------------------------
extern "C" void kernel_launch(void* const* d_in, const int* in_sizes, int n_in,
                              void* d_out, int out_size, void* d_ws, size_t ws_size,
                              hipStream_t stream)
{
    const float* x  = (const float*)d_in[0];
    const float* Wq = (const float*)d_in[1];
    const float* bq = (const float*)d_in[2];
    const float* Wk = (const float*)d_in[3];
    const float* bk = (const float*)d_in[4];
    const float* Wv = (const float*)d_in[5];
    const float* bv = (const float*)d_in[6];
    float* out = (float*)d_out;

    float* ws = (float*)d_ws;
    const size_t NS = (size_t)H * W * W;      // 2M floats

    float* Sd = ws;
    float* vh = ws + NS;

    k_rowA<<<dim3(H, 2), 512, 0, stream>>>(x, Wq, bq, Wk, bk, Wv, bv, Sd, vh);
    k_rowB<<<dim3(H, 2), 512, 0, stream>>>(Sd, vh, out);
}